// Round 1
// baseline (22195.645 us; speedup 1.0000x reference)
//
#include <hip/hip_runtime.h>
#include <hip/hip_bf16.h>

// Sizes (fixed by the problem)
#define BB 8
#define SS 512
#define CC 768
#define HH 12
#define HD 64
#define EE 8
#define KK 2
#define MLPH 3072
#define NT (BB*SS)            // 4096 tokens
#define NOUT (NT*CC)          // 3145728

// ---------------- Router: logits, softmax, top-2 weights, stats ----------------
__global__ __launch_bounds__(64) void router_kernel(const float* __restrict__ x,
    const float* __restrict__ et, float* __restrict__ W, float* __restrict__ stats)
{
    int t = blockIdx.x;
    int lane = threadIdx.x;
    const float* xr = x + (size_t)t * CC;
    float acc[EE] = {};
    for (int c = lane; c < CC; c += 64) {
        float xv = xr[c];
#pragma unroll
        for (int e = 0; e < EE; e++) acc[e] += xv * et[e * CC + c];
    }
#pragma unroll
    for (int e = 0; e < EE; e++) {
        for (int off = 32; off > 0; off >>= 1) acc[e] += __shfl_down(acc[e], off);
    }
    if (lane == 0) {
        const float inv = 0.03608439182435161f; // 1/sqrt(768)
        float l[EE], m = -1e30f;
#pragma unroll
        for (int e = 0; e < EE; e++) { l[e] = acc[e] * inv; m = fmaxf(m, l[e]); }
        float p[EE], sum = 0.f;
#pragma unroll
        for (int e = 0; e < EE; e++) { p[e] = expf(l[e] - m); sum += p[e]; }
        int i1 = 0;
#pragma unroll
        for (int e = 1; e < EE; e++) if (p[e] > p[i1]) i1 = e;
        int i2 = -1;
#pragma unroll
        for (int e = 0; e < EE; e++) if (e != i1 && (i2 < 0 || p[e] > p[i2])) i2 = e;
        float wn = p[i1] + p[i2];
#pragma unroll
        for (int e = 0; e < EE; e++) W[t * EE + e] = 0.f;
        W[t * EE + i1] = p[i1] / wn;
        W[t * EE + i2] = p[i2] / wn;
#pragma unroll
        for (int e = 0; e < EE; e++) atomicAdd(&stats[e], p[e] / sum);
        atomicAdd(&stats[EE + i1], 1.0f);
        atomicAdd(&stats[EE + i2], 1.0f);
    }
}

// ---------------- LayerNorm (per token row of 768) ----------------
__global__ __launch_bounds__(256) void ln_kernel(const float* __restrict__ x,
    const float* __restrict__ g, const float* __restrict__ b, float* __restrict__ outp)
{
    int t = blockIdx.x;
    const float* xr = x + (size_t)t * CC;
    __shared__ float red[256];
    int tid = threadIdx.x;
    float v[3];
    float s = 0.f;
#pragma unroll
    for (int i = 0; i < 3; i++) { v[i] = xr[tid + i * 256]; s += v[i]; }
    red[tid] = s; __syncthreads();
    for (int off = 128; off > 0; off >>= 1) { if (tid < off) red[tid] += red[tid + off]; __syncthreads(); }
    float mu = red[0] / (float)CC;
    __syncthreads();
    float s2 = 0.f;
#pragma unroll
    for (int i = 0; i < 3; i++) { float d = v[i] - mu; s2 += d * d; }
    red[tid] = s2; __syncthreads();
    for (int off = 128; off > 0; off >>= 1) { if (tid < off) red[tid] += red[tid + off]; __syncthreads(); }
    float var = red[0] / (float)CC;
    float sc = rsqrtf(var + 1e-5f);
#pragma unroll
    for (int i = 0; i < 3; i++) {
        int c = tid + i * 256;
        outp[(size_t)t * CC + c] = (v[i] - mu) * sc * g[c] + b[c];
    }
}

// ---------------- Generic fp32 tiled GEMM with epilogues ----------------
// EPI 0: C = A@B + bias
// EPI 1: C = res + A@B + bias
// EPI 2: C = gelu_exact(A@B + bias)
// EPI 3: C += wcol[row*8] * (res + A@B + bias)   (combine accumulate)
template<int EPI>
__global__ __launch_bounds__(256) void gemm64(
    const float* __restrict__ A, const float* __restrict__ Bm,
    const float* __restrict__ bias, const float* __restrict__ res,
    const float* __restrict__ wcol, float* __restrict__ Cout,
    int M, int N, int Kdim)
{
    __shared__ float sA[16][65];
    __shared__ float sB[16][65];
    int tid = threadIdx.x;
    int bm = blockIdx.y * 64, bn = blockIdx.x * 64;
    int tx = tid & 15, ty = tid >> 4;
    float accv[4][4] = {};
    for (int k0 = 0; k0 < Kdim; k0 += 16) {
#pragma unroll
        for (int i = 0; i < 4; i++) {
            int lin = tid + i * 256;
            int m = lin >> 4, kk = lin & 15;
            sA[kk][m] = A[(size_t)(bm + m) * Kdim + k0 + kk];
        }
#pragma unroll
        for (int i = 0; i < 4; i++) {
            int lin = tid + i * 256;
            int kk = lin >> 6, n = lin & 63;
            sB[kk][n] = Bm[(size_t)(k0 + kk) * N + bn + n];
        }
        __syncthreads();
#pragma unroll
        for (int kk = 0; kk < 16; kk++) {
            float a[4], b[4];
#pragma unroll
            for (int i = 0; i < 4; i++) a[i] = sA[kk][ty * 4 + i];
#pragma unroll
            for (int j = 0; j < 4; j++) b[j] = sB[kk][tx * 4 + j];
#pragma unroll
            for (int i = 0; i < 4; i++)
#pragma unroll
                for (int j = 0; j < 4; j++)
                    accv[i][j] += a[i] * b[j];
        }
        __syncthreads();
    }
#pragma unroll
    for (int i = 0; i < 4; i++) {
        int gm = bm + ty * 4 + i;
#pragma unroll
        for (int j = 0; j < 4; j++) {
            int gn = bn + tx * 4 + j;
            float v = accv[i][j] + bias[gn];
            size_t idx = (size_t)gm * N + gn;
            if (EPI == 0) {
                Cout[idx] = v;
            } else if (EPI == 1) {
                Cout[idx] = res[idx] + v;
            } else if (EPI == 2) {
                Cout[idx] = 0.5f * v * (1.0f + erff(v * 0.70710678118654752f));
            } else {
                float y = res[idx] + v;
                Cout[idx] += wcol[(size_t)gm * EE] * y;
            }
        }
    }
}

// ---------------- Attention: one workgroup per (b, h, q-row) ----------------
__global__ __launch_bounds__(256) void attn_kernel(const float* __restrict__ qkv, float* __restrict__ o)
{
    int q = blockIdx.x & (SS - 1);
    int bh = blockIdx.x >> 9;
    int h = bh % HH, b = bh / HH;
    int tq = b * SS + q;
    __shared__ float qs[HD];
    __shared__ float sc[SS];
    __shared__ float red2[256];
    __shared__ float opart[4][HD];
    int tid = threadIdx.x;
    const float* qptr = qkv + (size_t)tq * (3 * CC) + h * HD;
    if (tid < HD) qs[tid] = qptr[tid];
    __syncthreads();
    // scores (x8 scale per reference: logits * sqrt(HD))
#pragma unroll
    for (int r = 0; r < 2; r++) {
        int j = tid + r * 256;
        const float* kptr = qkv + (size_t)(b * SS + j) * (3 * CC) + CC + h * HD;
        float s = 0.f;
        for (int d = 0; d < HD; d++) s += qs[d] * kptr[d];
        sc[j] = s * 8.0f;
    }
    __syncthreads();
    float m = fmaxf(sc[tid], sc[tid + 256]);
    red2[tid] = m; __syncthreads();
    for (int off = 128; off > 0; off >>= 1) { if (tid < off) red2[tid] = fmaxf(red2[tid], red2[tid + off]); __syncthreads(); }
    m = red2[0];
    __syncthreads();
    float ssum = 0.f;
#pragma unroll
    for (int r = 0; r < 2; r++) {
        int j = tid + r * 256;
        float p = expf(sc[j] - m);
        sc[j] = p;
        ssum += p;
    }
    red2[tid] = ssum; __syncthreads();
    for (int off = 128; off > 0; off >>= 1) { if (tid < off) red2[tid] += red2[tid + off]; __syncthreads(); }
    float denom = red2[0];
    __syncthreads();
    int w = tid >> 6, d = tid & 63;
    float acc = 0.f;
    const float* vbase = qkv + (size_t)(b * SS) * (3 * CC) + 2 * CC + h * HD + d;
    for (int j = w * 128; j < w * 128 + 128; j++) {
        acc += sc[j] * vbase[(size_t)j * (3 * CC)];
    }
    opart[w][d] = acc; __syncthreads();
    if (tid < HD) {
        float od = (opart[0][tid] + opart[1][tid] + opart[2][tid] + opart[3][tid]) / denom;
        o[(size_t)tq * CC + h * HD + tid] = od;
    }
}

// ---------------- Final: out = x + combine ----------------
__global__ __launch_bounds__(256) void final_add(const float* __restrict__ x,
    const float* __restrict__ comb, float* __restrict__ outp)
{
    int i = blockIdx.x * 256 + threadIdx.x;
    const float4* x4 = (const float4*)x;
    const float4* c4 = (const float4*)comb;
    float4* o4 = (float4*)outp;
    float4 a = x4[i], c = c4[i];
    a.x += c.x; a.y += c.y; a.z += c.z; a.w += c.w;
    o4[i] = a;
}

// ---------------- Balance loss ----------------
__global__ __launch_bounds__(256) void loss_kernel(const float* __restrict__ et,
    const float* __restrict__ stats, float* __restrict__ out_loss)
{
    __shared__ float red[256];
    int tid = threadIdx.x;
    float s = 0.f;
    for (int i = tid; i < EE * CC; i += 256) { float v = et[i]; s += v * v; }
    red[tid] = s; __syncthreads();
    for (int off = 128; off > 0; off >>= 1) { if (tid < off) red[tid] += red[tid + off]; __syncthreads(); }
    if (tid == 0) {
        float bl = 0.f;
        for (int e = 0; e < EE; e++) {
            float f = stats[EE + e] / (float)(NT * KK);
            float P = stats[e] / (float)NT;
            bl += f * P;
        }
        bl = (float)EE * bl + 0.01f * sqrtf(red[0]);
        *out_loss = bl;
    }
}

extern "C" void kernel_launch(void* const* d_in, const int* in_sizes, int n_in,
                              void* d_out, int out_size, void* d_ws, size_t ws_size,
                              hipStream_t stream) {
    const float* x      = (const float*)d_in[0];
    const float* et     = (const float*)d_in[1];
    const float* ln1_g  = (const float*)d_in[2];
    const float* ln1_b  = (const float*)d_in[3];
    const float* qkv_w  = (const float*)d_in[4];
    const float* qkv_b  = (const float*)d_in[5];
    const float* proj_w = (const float*)d_in[6];
    const float* proj_b = (const float*)d_in[7];
    const float* ln2_g  = (const float*)d_in[8];
    const float* ln2_b  = (const float*)d_in[9];
    const float* fc1_w  = (const float*)d_in[10];
    const float* fc1_b  = (const float*)d_in[11];
    const float* fc2_w  = (const float*)d_in[12];
    const float* fc2_b  = (const float*)d_in[13];
    float* outp = (float*)d_out;
    float* ws = (float*)d_ws;

    // workspace layout (floats)
    float* W     = ws;                       // 4096*8
    float* stats = ws + 32768;               // 16 (+pad)
    float* comb  = ws + 32832;               // 3145728
    float* h     = comb + NOUT;              // 3145728
    float* xmid  = h + NOUT;                 // 3145728
    float* big   = xmid + NOUT;              // 12582912 (qkv | o, aliased by mlp1)
    float* qkv   = big;                      // 4096*2304
    float* o     = big + (size_t)NT * 3 * CC;// 3145728
    float* mlp1  = big;                      // 4096*3072 (aliases qkv+o, both dead by then)

    hipMemsetAsync(stats, 0, 16 * sizeof(float), stream);
    hipMemsetAsync(comb, 0, (size_t)NOUT * sizeof(float), stream);

    router_kernel<<<NT, 64, 0, stream>>>(x, et, W, stats);

    for (int e = 0; e < EE; e++) {
        ln_kernel<<<NT, 256, 0, stream>>>(x, ln1_g + e * CC, ln1_b + e * CC, h);
        gemm64<0><<<dim3((3 * CC) / 64, NT / 64), 256, 0, stream>>>(
            h, qkv_w + (size_t)e * CC * 3 * CC, qkv_b + e * 3 * CC, nullptr, nullptr, qkv,
            NT, 3 * CC, CC);
        attn_kernel<<<BB * HH * SS, 256, 0, stream>>>(qkv, o);
        gemm64<1><<<dim3(CC / 64, NT / 64), 256, 0, stream>>>(
            o, proj_w + (size_t)e * CC * CC, proj_b + e * CC, x, nullptr, xmid,
            NT, CC, CC);
        ln_kernel<<<NT, 256, 0, stream>>>(xmid, ln2_g + e * CC, ln2_b + e * CC, h);
        gemm64<2><<<dim3(MLPH / 64, NT / 64), 256, 0, stream>>>(
            h, fc1_w + (size_t)e * CC * MLPH, fc1_b + e * MLPH, nullptr, nullptr, mlp1,
            NT, MLPH, CC);
        gemm64<3><<<dim3(CC / 64, NT / 64), 256, 0, stream>>>(
            mlp1, fc2_w + (size_t)e * MLPH * CC, fc2_b + e * CC, xmid, W + e, comb,
            NT, CC, MLPH);
    }

    final_add<<<NOUT / 4 / 256, 256, 0, stream>>>(x, comb, outp);
    loss_kernel<<<1, 256, 0, stream>>>(et, stats, outp + NOUT);
}

// Round 2
// 5200.304 us; speedup vs baseline: 4.2681x; 4.2681x over previous
//
#include <hip/hip_runtime.h>
#include <hip/hip_bf16.h>

#define BB 8
#define SS 512
#define CC 768
#define HH 12
#define HD 64
#define EE 8
#define KK 2
#define MLPH 3072
#define NT (BB*SS)            // 4096 tokens
#define NOUT (NT*CC)          // 3145728

typedef unsigned int u32;
typedef unsigned short u16;
typedef __attribute__((ext_vector_type(8))) short short8;
typedef __attribute__((ext_vector_type(4))) float f32x4;

__device__ __forceinline__ u16 f2bf(float f) {
    u32 u = __builtin_bit_cast(u32, f);
    u32 r = (u + 0x7fffu + ((u >> 16) & 1u)) >> 16;
    return (u16)r;
}
__device__ __forceinline__ float bf2f(u16 h) {
    u32 u = ((u32)h) << 16;
    return __builtin_bit_cast(float, u);
}
__device__ __forceinline__ void gl_lds16(const void* g, void* l) {
    __builtin_amdgcn_global_load_lds(
        (const __attribute__((address_space(1))) u32*)g,
        (__attribute__((address_space(3))) u32*)l, 16, 0, 0);
}

// ---------------- Router ----------------
__global__ __launch_bounds__(64) void router_kernel(const float* __restrict__ x,
    const float* __restrict__ et, float* __restrict__ W, float* __restrict__ stats)
{
    int t = blockIdx.x;
    int lane = threadIdx.x;
    const float* xr = x + (size_t)t * CC;
    float acc[EE] = {};
    for (int c = lane; c < CC; c += 64) {
        float xv = xr[c];
#pragma unroll
        for (int e = 0; e < EE; e++) acc[e] += xv * et[e * CC + c];
    }
#pragma unroll
    for (int e = 0; e < EE; e++) {
        for (int off = 32; off > 0; off >>= 1) acc[e] += __shfl_down(acc[e], off);
    }
    if (lane == 0) {
        const float inv = 0.03608439182435161f; // 1/sqrt(768)
        float l[EE], m = -1e30f;
#pragma unroll
        for (int e = 0; e < EE; e++) { l[e] = acc[e] * inv; m = fmaxf(m, l[e]); }
        float p[EE], sum = 0.f;
#pragma unroll
        for (int e = 0; e < EE; e++) { p[e] = expf(l[e] - m); sum += p[e]; }
        int i1 = 0;
#pragma unroll
        for (int e = 1; e < EE; e++) if (p[e] > p[i1]) i1 = e;
        int i2 = -1;
#pragma unroll
        for (int e = 0; e < EE; e++) if (e != i1 && (i2 < 0 || p[e] > p[i2])) i2 = e;
        float wn = p[i1] + p[i2];
#pragma unroll
        for (int e = 0; e < EE; e++) W[t * EE + e] = 0.f;
        W[t * EE + i1] = p[i1] / wn;
        W[t * EE + i2] = p[i2] / wn;
#pragma unroll
        for (int e = 0; e < EE; e++) atomicAdd(&stats[e], p[e] / sum);
        atomicAdd(&stats[EE + i1], 1.0f);
        atomicAdd(&stats[EE + i2], 1.0f);
    }
}

// ---------------- LayerNorm (templated output dtype) ----------------
template<int BF16OUT>
__global__ __launch_bounds__(256) void ln_kernel(const float* __restrict__ x,
    const float* __restrict__ g, const float* __restrict__ b, void* __restrict__ outp)
{
    int t = blockIdx.x;
    const float* xr = x + (size_t)t * CC;
    __shared__ float red[256];
    int tid = threadIdx.x;
    float v[3];
    float s = 0.f;
#pragma unroll
    for (int i = 0; i < 3; i++) { v[i] = xr[tid + i * 256]; s += v[i]; }
    red[tid] = s; __syncthreads();
    for (int off = 128; off > 0; off >>= 1) { if (tid < off) red[tid] += red[tid + off]; __syncthreads(); }
    float mu = red[0] / (float)CC;
    __syncthreads();
    float s2 = 0.f;
#pragma unroll
    for (int i = 0; i < 3; i++) { float d = v[i] - mu; s2 += d * d; }
    red[tid] = s2; __syncthreads();
    for (int off = 128; off > 0; off >>= 1) { if (tid < off) red[tid] += red[tid + off]; __syncthreads(); }
    float var = red[0] / (float)CC;
    float sc = rsqrtf(var + 1e-5f);
#pragma unroll
    for (int i = 0; i < 3; i++) {
        int c = tid + i * 256;
        float val = (v[i] - mu) * sc * g[c] + b[c];
        if (BF16OUT) ((u16*)outp)[(size_t)t * CC + c] = f2bf(val);
        else         ((float*)outp)[(size_t)t * CC + c] = val;
    }
}

// ---------------- fp32 tiled GEMM (qkv only; accuracy-critical path) ----------------
__global__ __launch_bounds__(256) void gemm64(
    const float* __restrict__ A, const float* __restrict__ Bm,
    const float* __restrict__ bias, float* __restrict__ Cout,
    int M, int N, int Kdim)
{
    __shared__ float sA[16][65];
    __shared__ float sB[16][65];
    int tid = threadIdx.x;
    int bm = blockIdx.y * 64, bn = blockIdx.x * 64;
    int tx = tid & 15, ty = tid >> 4;
    float accv[4][4] = {};
    for (int k0 = 0; k0 < Kdim; k0 += 16) {
#pragma unroll
        for (int i = 0; i < 4; i++) {
            int lin = tid + i * 256;
            int m = lin >> 4, kk = lin & 15;
            sA[kk][m] = A[(size_t)(bm + m) * Kdim + k0 + kk];
        }
#pragma unroll
        for (int i = 0; i < 4; i++) {
            int lin = tid + i * 256;
            int kk = lin >> 6, n = lin & 63;
            sB[kk][n] = Bm[(size_t)(k0 + kk) * N + bn + n];
        }
        __syncthreads();
#pragma unroll
        for (int kk = 0; kk < 16; kk++) {
            float a[4], b[4];
#pragma unroll
            for (int i = 0; i < 4; i++) a[i] = sA[kk][ty * 4 + i];
#pragma unroll
            for (int j = 0; j < 4; j++) b[j] = sB[kk][tx * 4 + j];
#pragma unroll
            for (int i = 0; i < 4; i++)
#pragma unroll
                for (int j = 0; j < 4; j++)
                    accv[i][j] += a[i] * b[j];
        }
        __syncthreads();
    }
#pragma unroll
    for (int i = 0; i < 4; i++) {
        int gm = bm + ty * 4 + i;
#pragma unroll
        for (int j = 0; j < 4; j++) {
            int gn = bn + tx * 4 + j;
            Cout[(size_t)gm * N + gn] = accv[i][j] + bias[gn];
        }
    }
}

// ---------------- weight transpose+convert: src fp32 [K][N] -> dst bf16 [N][K] ----------------
__global__ __launch_bounds__(256) void transpose_w(const float* __restrict__ src,
    u16* __restrict__ dst, int Kdim, int N)
{
    __shared__ float tile[32][33];
    int n0 = blockIdx.x * 32, k0 = blockIdx.y * 32;
    int tx = threadIdx.x & 31, ty = threadIdx.x >> 5;  // ty 0..7
#pragma unroll
    for (int i = 0; i < 32; i += 8)
        tile[ty + i][tx] = src[(size_t)(k0 + ty + i) * N + n0 + tx];
    __syncthreads();
#pragma unroll
    for (int i = 0; i < 32; i += 8)
        dst[(size_t)(n0 + ty + i) * Kdim + k0 + tx] = f2bf(tile[tx][ty + i]);
}

// ---------------- bf16 MFMA GEMM, 128x128 tile, BK=32 (m97 structure) ----------------
// A [M][K] bf16, BT [N][K] bf16. EPI: 1: out=res+AB+bias (f32)
// 2: out=gelu(AB+bias) (bf16)   3: out += wcol[gm*8]*(res+AB+bias) (f32)
template<int EPI>
__global__ __launch_bounds__(256) void gemm_mfma(
    const u16* __restrict__ A, const u16* __restrict__ BT,
    const float* __restrict__ bias, const float* __restrict__ res,
    const float* __restrict__ wcol, void* __restrict__ Cout,
    int M, int N, int Kdim)
{
    __shared__ u16 sA[128 * 32];
    __shared__ u16 sB[128 * 32];
    int tid = threadIdx.x;
    int wid = tid >> 6, lane = tid & 63;
    int bm = blockIdx.y * 128, bn = blockIdx.x * 128;
    int wr = wid >> 1, wc = wid & 1;
    int la = lane & 15, lb = lane >> 4;
    const f32x4 zero = {0.f, 0.f, 0.f, 0.f};
    f32x4 acc[4][4];
#pragma unroll
    for (int i = 0; i < 4; i++)
#pragma unroll
        for (int j = 0; j < 4; j++) acc[i][j] = zero;

    for (int k0 = 0; k0 < Kdim; k0 += 32) {
#pragma unroll
        for (int it = 0; it < 2; it++) {
            int cbase = (wid * 2 + it) * 64;      // wave-uniform chunk base
            int cidx = cbase + lane;
            int row = cidx >> 2, kc = (cidx & 3) * 8;
            gl_lds16(A  + (size_t)(bm + row) * Kdim + k0 + kc, sA + cbase * 8);
            gl_lds16(BT + (size_t)(bn + row) * Kdim + k0 + kc, sB + cbase * 8);
        }
        __syncthreads();
        short8 av[4], bv[4];
#pragma unroll
        for (int i = 0; i < 4; i++)
            av[i] = *(const short8*)(sA + (size_t)(wr * 64 + i * 16 + la) * 32 + lb * 8);
#pragma unroll
        for (int j = 0; j < 4; j++)
            bv[j] = *(const short8*)(sB + (size_t)(wc * 64 + j * 16 + la) * 32 + lb * 8);
#pragma unroll
        for (int i = 0; i < 4; i++)
#pragma unroll
            for (int j = 0; j < 4; j++)
                acc[i][j] = __builtin_amdgcn_mfma_f32_16x16x32_bf16(av[i], bv[j], acc[i][j], 0, 0, 0);
        __syncthreads();
    }
    // epilogue: C/D layout col=lane&15, row=(lane>>4)*4+reg   [m89 verified]
#pragma unroll
    for (int i = 0; i < 4; i++) {
#pragma unroll
        for (int j = 0; j < 4; j++) {
            int gn = bn + wc * 64 + j * 16 + la;
            float bsv = bias[gn];
#pragma unroll
            for (int r = 0; r < 4; r++) {
                int gm = bm + wr * 64 + i * 16 + lb * 4 + r;
                size_t idx = (size_t)gm * N + gn;
                float v = acc[i][j][r] + bsv;
                if (EPI == 1) {
                    ((float*)Cout)[idx] = res[idx] + v;
                } else if (EPI == 2) {
                    float gel = 0.5f * v * (1.0f + erff(v * 0.70710678118654752f));
                    ((u16*)Cout)[idx] = f2bf(gel);
                } else {
                    float y = res[idx] + v;
                    ((float*)Cout)[idx] += wcol[(size_t)gm * EE] * y;
                }
            }
        }
    }
}

// ---------------- Flash attention, fp32: one block per (b,h,64-q-tile) ----------------
__global__ __launch_bounds__(256) void attn_flash(const float* __restrict__ qkv, u16* __restrict__ o)
{
    int q0 = blockIdx.x * 64;
    int h = blockIdx.y, b = blockIdx.z;
    __shared__ float Qs[64][64];
    __shared__ float Ks[64][64];
    __shared__ float Vs[64][64];
    __shared__ float Ps[64][65];
    int tid = threadIdx.x;
    int ty = tid >> 4, tx = tid & 15;
    const size_t rs3 = 3 * CC;
    const float* base = qkv + (size_t)(b * SS) * rs3 + h * HD;

    // stage Q tile (granule-XOR swizzle: granule g of row r stored at g^(r>>2))
#pragma unroll
    for (int rr = 0; rr < 4; rr++) {
        int r = rr * 16 + ty;
        int sc_ = ((tx ^ (r >> 2)) & 15) * 4;
        *(float4*)&Qs[r][sc_] = *(const float4*)(base + (size_t)(q0 + r) * rs3 + tx * 4);
    }
    float m_r[4], l_r[4], O_r[4][4];
#pragma unroll
    for (int i = 0; i < 4; i++) {
        m_r[i] = -1e30f; l_r[i] = 0.f;
#pragma unroll
        for (int j = 0; j < 4; j++) O_r[i][j] = 0.f;
    }

    for (int kt = 0; kt < SS; kt += 64) {
#pragma unroll
        for (int rr = 0; rr < 4; rr++) {
            int r = rr * 16 + ty;
            int sc_ = ((tx ^ (r >> 2)) & 15) * 4;
            *(float4*)&Ks[r][sc_] = *(const float4*)(base + (size_t)(kt + r) * rs3 + CC + tx * 4);
            *(float4*)&Vs[r][sc_] = *(const float4*)(base + (size_t)(kt + r) * rs3 + 2 * CC + tx * 4);
        }
        __syncthreads();
        // S = (Q K^T) * 8
        float s[4][4] = {};
#pragma unroll
        for (int dg = 0; dg < 16; dg++) {
            float4 qa[4], kb[4];
#pragma unroll
            for (int i = 0; i < 4; i++) qa[i] = *(const float4*)&Qs[ty * 4 + i][((dg ^ ty) & 15) * 4];
#pragma unroll
            for (int j = 0; j < 4; j++) kb[j] = *(const float4*)&Ks[tx * 4 + j][((dg ^ tx) & 15) * 4];
#pragma unroll
            for (int i = 0; i < 4; i++)
#pragma unroll
                for (int j = 0; j < 4; j++)
                    s[i][j] += qa[i].x * kb[j].x + qa[i].y * kb[j].y + qa[i].z * kb[j].z + qa[i].w * kb[j].w;
        }
        // online softmax (row groups = 16 lanes sharing ty)
#pragma unroll
        for (int i = 0; i < 4; i++) {
#pragma unroll
            for (int j = 0; j < 4; j++) s[i][j] *= 8.f;
            float mx = fmaxf(fmaxf(s[i][0], s[i][1]), fmaxf(s[i][2], s[i][3]));
            for (int off = 1; off < 16; off <<= 1) mx = fmaxf(mx, __shfl_xor(mx, off, 64));
            float mn = fmaxf(m_r[i], mx);
            float corr = __expf(m_r[i] - mn);
            m_r[i] = mn;
            float rsum = 0.f;
#pragma unroll
            for (int j = 0; j < 4; j++) { s[i][j] = __expf(s[i][j] - mn); rsum += s[i][j]; }
            for (int off = 1; off < 16; off <<= 1) rsum += __shfl_xor(rsum, off, 64);
            l_r[i] = l_r[i] * corr + rsum;
#pragma unroll
            for (int j = 0; j < 4; j++) O_r[i][j] *= corr;
#pragma unroll
            for (int j = 0; j < 4; j++) Ps[ty * 4 + i][tx * 4 + j] = s[i][j];
        }
        __syncthreads();
        // O += P @ V
#pragma unroll 4
        for (int k = 0; k < 64; k++) {
            float4 vv = *(const float4*)&Vs[k][((tx ^ (k >> 2)) & 15) * 4];
#pragma unroll
            for (int i = 0; i < 4; i++) {
                float p = Ps[ty * 4 + i][k];
                O_r[i][0] += p * vv.x; O_r[i][1] += p * vv.y;
                O_r[i][2] += p * vv.z; O_r[i][3] += p * vv.w;
            }
        }
        __syncthreads();
    }
    u16* obase = o + (size_t)(b * SS + q0) * CC + h * HD;
#pragma unroll
    for (int i = 0; i < 4; i++) {
        float inv = 1.f / l_r[i];
#pragma unroll
        for (int j = 0; j < 4; j++)
            obase[(size_t)(ty * 4 + i) * CC + tx * 4 + j] = f2bf(O_r[i][j] * inv);
    }
}

// ---------------- out = x + comb ----------------
__global__ __launch_bounds__(256) void final_add(const float* __restrict__ x,
    const float* __restrict__ comb, float* __restrict__ outp)
{
    int i = blockIdx.x * 256 + threadIdx.x;
    const float4* x4 = (const float4*)x;
    const float4* c4 = (const float4*)comb;
    float4* o4 = (float4*)outp;
    float4 a = x4[i], c = c4[i];
    a.x += c.x; a.y += c.y; a.z += c.z; a.w += c.w;
    o4[i] = a;
}

// ---------------- balance loss ----------------
__global__ __launch_bounds__(256) void loss_kernel(const float* __restrict__ et,
    const float* __restrict__ stats, float* __restrict__ out_loss)
{
    __shared__ float red[256];
    int tid = threadIdx.x;
    float s = 0.f;
    for (int i = tid; i < EE * CC; i += 256) { float v = et[i]; s += v * v; }
    red[tid] = s; __syncthreads();
    for (int off = 128; off > 0; off >>= 1) { if (tid < off) red[tid] += red[tid + off]; __syncthreads(); }
    if (tid == 0) {
        float bl = 0.f;
        for (int e = 0; e < EE; e++) {
            float f = stats[EE + e] / (float)(NT * KK);
            float P = stats[e] / (float)NT;
            bl += f * P;
        }
        *out_loss = (float)EE * bl + 0.01f * sqrtf(red[0]);
    }
}

extern "C" void kernel_launch(void* const* d_in, const int* in_sizes, int n_in,
                              void* d_out, int out_size, void* d_ws, size_t ws_size,
                              hipStream_t stream) {
    const float* x      = (const float*)d_in[0];
    const float* et     = (const float*)d_in[1];
    const float* ln1_g  = (const float*)d_in[2];
    const float* ln1_b  = (const float*)d_in[3];
    const float* qkv_w  = (const float*)d_in[4];
    const float* qkv_b  = (const float*)d_in[5];
    const float* proj_w = (const float*)d_in[6];
    const float* proj_b = (const float*)d_in[7];
    const float* ln2_g  = (const float*)d_in[8];
    const float* ln2_b  = (const float*)d_in[9];
    const float* fc1_w  = (const float*)d_in[10];
    const float* fc1_b  = (const float*)d_in[11];
    const float* fc2_w  = (const float*)d_in[12];
    const float* fc2_b  = (const float*)d_in[13];
    float* outp = (float*)d_out;
    char* base = (char*)d_ws;

    float* W     = (float*)(base);                       // 131072 B
    float* stats = (float*)(base + 131072);              // 64 B
    float* comb  = (float*)(base + 131584);              // 12582912
    float* xmid  = (float*)(base + 12714496);            // 12582912
    float* h32   = (float*)(base + 25297408);            // 12582912
    float* qkv   = (float*)(base + 37880320);            // 37748736
    u16*   hbf   = (u16*)  (base + 75629056);            // 6291456
    u16*   obf   = (u16*)  (base + 81920512);            // 6291456
    u16*   mlp1  = (u16*)  (base + 88211968);            // 25165824
    u16*   projT = (u16*)  (base + 113377792);           // 1179648
    u16*   fc1T  = (u16*)  (base + 114557440);           // 4718592
    u16*   fc2T  = (u16*)  (base + 119276032);           // 4718592

    hipMemsetAsync(stats, 0, 16 * sizeof(float), stream);
    hipMemsetAsync(comb, 0, (size_t)NOUT * sizeof(float), stream);

    router_kernel<<<NT, 64, 0, stream>>>(x, et, W, stats);

    for (int e = 0; e < EE; e++) {
        ln_kernel<0><<<NT, 256, 0, stream>>>(x, ln1_g + e * CC, ln1_b + e * CC, h32);
        gemm64<<<dim3((3 * CC) / 64, NT / 64), 256, 0, stream>>>(
            h32, qkv_w + (size_t)e * CC * 3 * CC, qkv_b + (size_t)e * 3 * CC, qkv,
            NT, 3 * CC, CC);
        attn_flash<<<dim3(SS / 64, HH, BB), 256, 0, stream>>>(qkv, obf);

        transpose_w<<<dim3(CC / 32, CC / 32), 256, 0, stream>>>(
            proj_w + (size_t)e * CC * CC, projT, CC, CC);
        gemm_mfma<1><<<dim3(CC / 128, NT / 128), 256, 0, stream>>>(
            obf, projT, proj_b + (size_t)e * CC, x, nullptr, xmid, NT, CC, CC);

        ln_kernel<1><<<NT, 256, 0, stream>>>(xmid, ln2_g + e * CC, ln2_b + e * CC, hbf);

        transpose_w<<<dim3(MLPH / 32, CC / 32), 256, 0, stream>>>(
            fc1_w + (size_t)e * CC * MLPH, fc1T, CC, MLPH);
        gemm_mfma<2><<<dim3(MLPH / 128, NT / 128), 256, 0, stream>>>(
            hbf, fc1T, fc1_b + (size_t)e * MLPH, nullptr, nullptr, mlp1, NT, MLPH, CC);

        transpose_w<<<dim3(CC / 32, MLPH / 32), 256, 0, stream>>>(
            fc2_w + (size_t)e * MLPH * CC, fc2T, MLPH, CC);
        gemm_mfma<3><<<dim3(CC / 128, NT / 128), 256, 0, stream>>>(
            mlp1, fc2T, fc2_b + (size_t)e * CC, xmid, W + e, comb, NT, CC, MLPH);
    }

    final_add<<<NOUT / 4 / 256, 256, 0, stream>>>(x, comb, outp);
    loss_kernel<<<1, 256, 0, stream>>>(et, stats, outp + NOUT);
}

// Round 4
// 2397.816 us; speedup vs baseline: 9.2566x; 2.1688x over previous
//
#include <hip/hip_runtime.h>
#include <hip/hip_bf16.h>

#define BB 8
#define SS 512
#define CC 768
#define HH 12
#define HD 64
#define EE 8
#define KK 2
#define MLPH 3072
#define NT (BB*SS)            // 4096 tokens
#define NOUT (NT*CC)          // 3145728

typedef unsigned int u32;
typedef unsigned short u16;
typedef __attribute__((ext_vector_type(8))) short short8;
typedef __attribute__((ext_vector_type(4))) float f32x4;

__device__ __forceinline__ u16 f2bf(float f) {
    u32 u = __builtin_bit_cast(u32, f);
    u32 r = (u + 0x7fffu + ((u >> 16) & 1u)) >> 16;
    return (u16)r;
}
__device__ __forceinline__ float bf2f(u16 h) {
    u32 u = ((u32)h) << 16;
    return __builtin_bit_cast(float, u);
}
__device__ __forceinline__ void gl_lds16(const void* g, void* l) {
    __builtin_amdgcn_global_load_lds(
        (const __attribute__((address_space(1))) u32*)g,
        (__attribute__((address_space(3))) u32*)l, 16, 0, 0);
}

// ---------------- Router: 64 blocks x 256, LDS et, block-level partials ----------------
__global__ __launch_bounds__(256) void router_kernel(const float* __restrict__ x,
    const float* __restrict__ et, float* __restrict__ W, float* __restrict__ stats)
{
    __shared__ float etl[EE * CC];
    __shared__ float pred[4][2 * EE];
    int tid = threadIdx.x;
    for (int i = tid; i < EE * CC; i += 256) etl[i] = et[i];
    __syncthreads();
    int wid = tid >> 6, lane = tid & 63;
    float psum[EE] = {}, csum[EE] = {};
    for (int i = 0; i < 16; i++) {
        int t = blockIdx.x * 64 + wid * 16 + i;
        const float* xr = x + (size_t)t * CC;
        float acc[EE] = {};
        for (int c = lane; c < CC; c += 64) {
            float xv = xr[c];
#pragma unroll
            for (int e = 0; e < EE; e++) acc[e] += xv * etl[e * CC + c];
        }
#pragma unroll
        for (int e = 0; e < EE; e++)
            for (int off = 1; off < 64; off <<= 1) acc[e] += __shfl_xor(acc[e], off, 64);
        if (lane == 0) {
            const float inv = 0.03608439182435161f; // 1/sqrt(768)
            float l[EE], m = -1e30f;
#pragma unroll
            for (int e = 0; e < EE; e++) { l[e] = acc[e] * inv; m = fmaxf(m, l[e]); }
            float p[EE], sum = 0.f;
#pragma unroll
            for (int e = 0; e < EE; e++) { p[e] = __expf(l[e] - m); sum += p[e]; }
            int i1 = 0;
#pragma unroll
            for (int e = 1; e < EE; e++) if (p[e] > p[i1]) i1 = e;
            int i2 = -1;
#pragma unroll
            for (int e = 0; e < EE; e++) if (e != i1 && (i2 < 0 || p[e] > p[i2])) i2 = e;
            float wn = p[i1] + p[i2];
#pragma unroll
            for (int e = 0; e < EE; e++) W[t * EE + e] = 0.f;
            W[t * EE + i1] = p[i1] / wn;
            W[t * EE + i2] = p[i2] / wn;
#pragma unroll
            for (int e = 0; e < EE; e++) psum[e] += p[e] / sum;
            csum[i1] += 1.f; csum[i2] += 1.f;
        }
    }
    if (lane == 0) {
#pragma unroll
        for (int e = 0; e < EE; e++) { pred[wid][e] = psum[e]; pred[wid][EE + e] = csum[e]; }
    }
    __syncthreads();
    if (tid < 2 * EE) {
        float s = pred[0][tid] + pred[1][tid] + pred[2][tid] + pred[3][tid];
        atomicAdd(&stats[tid], s);
    }
}

// ---------------- LayerNorm -> bf16 (optionally split hi+lo) ----------------
template<int SPLIT>
__global__ __launch_bounds__(256) void ln_kernel(const float* __restrict__ x,
    const float* __restrict__ g, const float* __restrict__ b,
    u16* __restrict__ out_hi, u16* __restrict__ out_lo)
{
    int t = blockIdx.x;
    const float* xr = x + (size_t)t * CC;
    __shared__ float red[256];
    int tid = threadIdx.x;
    float v[3];
    float s = 0.f;
#pragma unroll
    for (int i = 0; i < 3; i++) { v[i] = xr[tid + i * 256]; s += v[i]; }
    red[tid] = s; __syncthreads();
    for (int off = 128; off > 0; off >>= 1) { if (tid < off) red[tid] += red[tid + off]; __syncthreads(); }
    float mu = red[0] / (float)CC;
    __syncthreads();
    float s2 = 0.f;
#pragma unroll
    for (int i = 0; i < 3; i++) { float d = v[i] - mu; s2 += d * d; }
    red[tid] = s2; __syncthreads();
    for (int off = 128; off > 0; off >>= 1) { if (tid < off) red[tid] += red[tid + off]; __syncthreads(); }
    float var = red[0] / (float)CC;
    float sc = rsqrtf(var + 1e-5f);
#pragma unroll
    for (int i = 0; i < 3; i++) {
        int c = tid + i * 256;
        float val = (v[i] - mu) * sc * g[c] + b[c];
        u16 hi = f2bf(val);
        out_hi[(size_t)t * CC + c] = hi;
        if (SPLIT) out_lo[(size_t)t * CC + c] = f2bf(val - bf2f(hi));
    }
}

// ---------------- weight transpose+convert: fp32 [K][N] -> bf16 [N][K] (opt split) ----------------
template<int SPLIT>
__global__ __launch_bounds__(256) void transpose_w(const float* __restrict__ src,
    u16* __restrict__ dh, u16* __restrict__ dl, int Kdim, int N)
{
    __shared__ float tile[32][33];
    int n0 = blockIdx.x * 32, k0 = blockIdx.y * 32;
    int tx = threadIdx.x & 31, ty = threadIdx.x >> 5;
#pragma unroll
    for (int i = 0; i < 32; i += 8)
        tile[ty + i][tx] = src[(size_t)(k0 + ty + i) * N + n0 + tx];
    __syncthreads();
#pragma unroll
    for (int i = 0; i < 32; i += 8) {
        float v = tile[tx][ty + i];
        u16 hi = f2bf(v);
        dh[(size_t)(n0 + ty + i) * Kdim + k0 + tx] = hi;
        if (SPLIT) dl[(size_t)(n0 + ty + i) * Kdim + k0 + tx] = f2bf(v - bf2f(hi));
    }
}

// ---------------- split-precision qkv GEMM: acc = Ah*Bh + Ah*Bl + Al*Bh ----------------
// A* [4096][768], B* [2304][768]. cols<1536 -> qk hi/lo [M][1536]; cols>=1536 -> vt scatter
__global__ __launch_bounds__(256) void gemm_qkv_split(
    const u16* __restrict__ Ah, const u16* __restrict__ Al,
    const u16* __restrict__ Bh, const u16* __restrict__ Bl,
    const float* __restrict__ bias, u16* __restrict__ qk_hi,
    u16* __restrict__ qk_lo, u16* __restrict__ vtout)
{
    __shared__ u16 sAh[128 * 32], sAl[128 * 32], sBh[128 * 32], sBl[128 * 32];
    int tid = threadIdx.x;
    int wid = tid >> 6, lane = tid & 63;
    int bm = blockIdx.y * 128, bn = blockIdx.x * 128;
    int wr = wid >> 1, wc = wid & 1;
    int la = lane & 15, lb = lane >> 4;
    const f32x4 zero = {0.f, 0.f, 0.f, 0.f};
    f32x4 acc[4][4];
#pragma unroll
    for (int i = 0; i < 4; i++)
#pragma unroll
        for (int j = 0; j < 4; j++) acc[i][j] = zero;

    for (int k0 = 0; k0 < CC; k0 += 32) {
#pragma unroll
        for (int it = 0; it < 2; it++) {
            int cbase = (wid * 2 + it) * 64;
            int cidx = cbase + lane;
            int row = cidx >> 2, kc = (cidx & 3) * 8;
            size_t goffA = (size_t)(bm + row) * CC + k0 + kc;
            size_t goffB = (size_t)(bn + row) * CC + k0 + kc;
            gl_lds16(Ah + goffA, sAh + cbase * 8);
            gl_lds16(Al + goffA, sAl + cbase * 8);
            gl_lds16(Bh + goffB, sBh + cbase * 8);
            gl_lds16(Bl + goffB, sBl + cbase * 8);
        }
        __syncthreads();
        short8 avh[4], avl[4], bvh[4], bvl[4];
#pragma unroll
        for (int i = 0; i < 4; i++) {
            size_t off = (size_t)(wr * 64 + i * 16 + la) * 32 + lb * 8;
            avh[i] = *(const short8*)(sAh + off);
            avl[i] = *(const short8*)(sAl + off);
        }
#pragma unroll
        for (int j = 0; j < 4; j++) {
            size_t off = (size_t)(wc * 64 + j * 16 + la) * 32 + lb * 8;
            bvh[j] = *(const short8*)(sBh + off);
            bvl[j] = *(const short8*)(sBl + off);
        }
#pragma unroll
        for (int i = 0; i < 4; i++)
#pragma unroll
            for (int j = 0; j < 4; j++) {
                acc[i][j] = __builtin_amdgcn_mfma_f32_16x16x32_bf16(avh[i], bvh[j], acc[i][j], 0, 0, 0);
                acc[i][j] = __builtin_amdgcn_mfma_f32_16x16x32_bf16(avh[i], bvl[j], acc[i][j], 0, 0, 0);
                acc[i][j] = __builtin_amdgcn_mfma_f32_16x16x32_bf16(avl[i], bvh[j], acc[i][j], 0, 0, 0);
            }
        __syncthreads();
    }
#pragma unroll
    for (int i = 0; i < 4; i++) {
#pragma unroll
        for (int j = 0; j < 4; j++) {
            int gn = bn + wc * 64 + j * 16 + la;
            float bsv = bias[gn];
#pragma unroll
            for (int r = 0; r < 4; r++) {
                int gm = bm + wr * 64 + i * 16 + lb * 4 + r;
                float v = acc[i][j][r] + bsv;
                if (gn < 1536) {
                    u16 hi = f2bf(v);
                    qk_hi[(size_t)gm * 1536 + gn] = hi;
                    qk_lo[(size_t)gm * 1536 + gn] = f2bf(v - bf2f(hi));
                } else {
                    int dd = (gn - 1536) & 63, hh = (gn - 1536) >> 6;
                    int ss = gm & (SS - 1), bb = gm >> 9;
                    vtout[((size_t)((bb * HH + hh) * HD + dd)) * SS + ss] = f2bf(v);
                }
            }
        }
    }
}

// ---------------- plain bf16 MFMA GEMM, 128x128, BK=32 ----------------
// EPI 1: out=res+AB+bias (f32)  EPI 2: out=gelu(AB+bias) (bf16)
// EPI 3: out += wcol[gm*8]*(res+AB+bias) (f32)
template<int EPI>
__global__ __launch_bounds__(256) void gemm_mfma(
    const u16* __restrict__ A, const u16* __restrict__ BT,
    const float* __restrict__ bias, const float* __restrict__ res,
    const float* __restrict__ wcol, void* __restrict__ Cout,
    int M, int N, int Kdim)
{
    __shared__ u16 sA[128 * 32];
    __shared__ u16 sB[128 * 32];
    int tid = threadIdx.x;
    int wid = tid >> 6, lane = tid & 63;
    int bm = blockIdx.y * 128, bn = blockIdx.x * 128;
    int wr = wid >> 1, wc = wid & 1;
    int la = lane & 15, lb = lane >> 4;
    const f32x4 zero = {0.f, 0.f, 0.f, 0.f};
    f32x4 acc[4][4];
#pragma unroll
    for (int i = 0; i < 4; i++)
#pragma unroll
        for (int j = 0; j < 4; j++) acc[i][j] = zero;

    for (int k0 = 0; k0 < Kdim; k0 += 32) {
#pragma unroll
        for (int it = 0; it < 2; it++) {
            int cbase = (wid * 2 + it) * 64;
            int cidx = cbase + lane;
            int row = cidx >> 2, kc = (cidx & 3) * 8;
            gl_lds16(A  + (size_t)(bm + row) * Kdim + k0 + kc, sA + cbase * 8);
            gl_lds16(BT + (size_t)(bn + row) * Kdim + k0 + kc, sB + cbase * 8);
        }
        __syncthreads();
        short8 av[4], bv[4];
#pragma unroll
        for (int i = 0; i < 4; i++)
            av[i] = *(const short8*)(sA + (size_t)(wr * 64 + i * 16 + la) * 32 + lb * 8);
#pragma unroll
        for (int j = 0; j < 4; j++)
            bv[j] = *(const short8*)(sB + (size_t)(wc * 64 + j * 16 + la) * 32 + lb * 8);
#pragma unroll
        for (int i = 0; i < 4; i++)
#pragma unroll
            for (int j = 0; j < 4; j++)
                acc[i][j] = __builtin_amdgcn_mfma_f32_16x16x32_bf16(av[i], bv[j], acc[i][j], 0, 0, 0);
        __syncthreads();
    }
#pragma unroll
    for (int i = 0; i < 4; i++) {
#pragma unroll
        for (int j = 0; j < 4; j++) {
            int gn = bn + wc * 64 + j * 16 + la;
            float bsv = bias[gn];
#pragma unroll
            for (int r = 0; r < 4; r++) {
                int gm = bm + wr * 64 + i * 16 + lb * 4 + r;
                size_t idx = (size_t)gm * N + gn;
                float v = acc[i][j][r] + bsv;
                if (EPI == 1) {
                    ((float*)Cout)[idx] = res[idx] + v;
                } else if (EPI == 2) {
                    float gel = 0.5f * v * (1.0f + erff(v * 0.70710678118654752f));
                    ((u16*)Cout)[idx] = f2bf(gel);
                } else {
                    float y = res[idx] + v;
                    ((float*)Cout)[idx] += wcol[(size_t)gm * EE] * y;
                }
            }
        }
    }
}

// ---------------- MFMA flash attention with split-precision QK^T ----------------
// qk_hi/lo: bf16 [4096][1536] (q: cols 0..767, k: 768..1535); vt: bf16 [96][64][512]
__global__ __launch_bounds__(256) void attn_mfma(const u16* __restrict__ qk_hi,
    const u16* __restrict__ qk_lo, const u16* __restrict__ vt, u16* __restrict__ o)
{
    int q0 = blockIdx.x * 64;
    int h = blockIdx.y, b = blockIdx.z;
    int tid = threadIdx.x, wid = tid >> 6, lane = tid & 63;
    int la = lane & 15, lb = lane >> 4;
    __shared__ __align__(16) u16 Ksh[64 * 64];
    __shared__ __align__(16) u16 Ksl[64 * 64];
    __shared__ __align__(16) u16 Vs[64 * 64];
    __shared__ __align__(16) u16 Ps[4][16 * 64];

    short8 aqh[2], aql[2];
    {
        size_t qoff = (size_t)(b * SS + q0 + wid * 16 + la) * 1536 + h * HD;
#pragma unroll
        for (int kc = 0; kc < 2; kc++) {
            aqh[kc] = *(const short8*)(qk_hi + qoff + kc * 32 + lb * 8);
            aql[kc] = *(const short8*)(qk_lo + qoff + kc * 32 + lb * 8);
        }
    }
    const u16* kbh = qk_hi + (size_t)(b * SS) * 1536 + CC + h * HD;
    const u16* kbl = qk_lo + (size_t)(b * SS) * 1536 + CC + h * HD;
    const u16* vtbase = vt + (size_t)((b * HH + h) * HD) * SS;

    float m_r[4], l_r[4];
    f32x4 acc_o[4];
#pragma unroll
    for (int r = 0; r < 4; r++) { m_r[r] = -1e30f; l_r[r] = 0.f; }
#pragma unroll
    for (int d0 = 0; d0 < 4; d0++) acc_o[d0] = (f32x4){0.f, 0.f, 0.f, 0.f};

    for (int kt = 0; kt < SS; kt += 64) {
#pragma unroll
        for (int it = 0; it < 2; it++) {
            int base = it * 256 + wid * 64;
            int c = base + lane;
            int row = c >> 3;
            int gk = (c & 7) ^ (row & 7);          // pre-swizzled global source (m173)
            gl_lds16(kbh + (size_t)(kt + row) * 1536 + gk * 8, Ksh + base * 8);
            gl_lds16(kbl + (size_t)(kt + row) * 1536 + gk * 8, Ksl + base * 8);
            gl_lds16(vtbase + (size_t)row * SS + kt + gk * 8, Vs + base * 8);
        }
        __syncthreads();

        // S = Q K^T split: qh*kh + ql*kh + qh*kl
        f32x4 s4[4];
#pragma unroll
        for (int j = 0; j < 4; j++) s4[j] = (f32x4){0.f, 0.f, 0.f, 0.f};
#pragma unroll
        for (int kc = 0; kc < 2; kc++)
#pragma unroll
            for (int j = 0; j < 4; j++) {
                size_t off = (size_t)(j * 16 + la) * 64 + (((kc * 4 + lb) ^ (la & 7)) * 8);
                short8 bkh = *(const short8*)(Ksh + off);
                short8 bkl = *(const short8*)(Ksl + off);
                s4[j] = __builtin_amdgcn_mfma_f32_16x16x32_bf16(aqh[kc], bkh, s4[j], 0, 0, 0);
                s4[j] = __builtin_amdgcn_mfma_f32_16x16x32_bf16(aql[kc], bkh, s4[j], 0, 0, 0);
                s4[j] = __builtin_amdgcn_mfma_f32_16x16x32_bf16(aqh[kc], bkl, s4[j], 0, 0, 0);
            }
#pragma unroll
        for (int j = 0; j < 4; j++) s4[j] = s4[j] * 8.f;   // reference multiplies by sqrt(HD)

        // online softmax; lane owns rows lb*4+r, cols j*16+la
#pragma unroll
        for (int r = 0; r < 4; r++) {
            float mx = fmaxf(fmaxf(s4[0][r], s4[1][r]), fmaxf(s4[2][r], s4[3][r]));
#pragma unroll
            for (int off = 1; off < 16; off <<= 1) mx = fmaxf(mx, __shfl_xor(mx, off, 64));
            float mn = fmaxf(m_r[r], mx);
            float corr = __expf(m_r[r] - mn);
            m_r[r] = mn;
            float rs = 0.f;
#pragma unroll
            for (int j = 0; j < 4; j++) {
                float p = __expf(s4[j][r] - mn);
                s4[j][r] = p; rs += p;
            }
#pragma unroll
            for (int off = 1; off < 16; off <<= 1) rs += __shfl_xor(rs, off, 64);
            l_r[r] = l_r[r] * corr + rs;
#pragma unroll
            for (int d0 = 0; d0 < 4; d0++) acc_o[d0][r] = acc_o[d0][r] * corr;
        }
        // P -> per-wave LDS (XOR-swizzled), then A-frags
#pragma unroll
        for (int j = 0; j < 4; j++)
#pragma unroll
            for (int r = 0; r < 4; r++) {
                int row = lb * 4 + r;
                int sg = (2 * j + (la >> 3)) ^ (row & 7);
                Ps[wid][row * 64 + sg * 8 + (la & 7)] = f2bf(s4[j][r]);
            }
        short8 pa[2];
#pragma unroll
        for (int kc = 0; kc < 2; kc++)
            pa[kc] = *(const short8*)(&Ps[wid][la * 64 + (((kc * 4 + lb) ^ (la & 7)) * 8)]);
        // O += P @ V
#pragma unroll
        for (int d0 = 0; d0 < 4; d0++)
#pragma unroll
            for (int kc = 0; kc < 2; kc++) {
                short8 bv = *(const short8*)(&Vs[(d0 * 16 + la) * 64 + (((kc * 4 + lb) ^ (la & 7)) * 8)]);
                acc_o[d0] = __builtin_amdgcn_mfma_f32_16x16x32_bf16(pa[kc], bv, acc_o[d0], 0, 0, 0);
            }
        __syncthreads();
    }
#pragma unroll
    for (int r = 0; r < 4; r++) {
        float invl = 1.f / l_r[r];
        int tok = b * SS + q0 + wid * 16 + lb * 4 + r;
#pragma unroll
        for (int d0 = 0; d0 < 4; d0++)
            o[(size_t)tok * CC + h * HD + d0 * 16 + la] = f2bf(acc_o[d0][r] * invl);
    }
}

// ---------------- out = x + comb ----------------
__global__ __launch_bounds__(256) void final_add(const float* __restrict__ x,
    const float* __restrict__ comb, float* __restrict__ outp)
{
    int i = blockIdx.x * 256 + threadIdx.x;
    const float4* x4 = (const float4*)x;
    const float4* c4 = (const float4*)comb;
    float4* o4 = (float4*)outp;
    float4 a = x4[i], c = c4[i];
    a.x += c.x; a.y += c.y; a.z += c.z; a.w += c.w;
    o4[i] = a;
}

// ---------------- balance loss ----------------
__global__ __launch_bounds__(256) void loss_kernel(const float* __restrict__ et,
    const float* __restrict__ stats, float* __restrict__ out_loss)
{
    __shared__ float red[256];
    int tid = threadIdx.x;
    float s = 0.f;
    for (int i = tid; i < EE * CC; i += 256) { float v = et[i]; s += v * v; }
    red[tid] = s; __syncthreads();
    for (int off = 128; off > 0; off >>= 1) { if (tid < off) red[tid] += red[tid + off]; __syncthreads(); }
    if (tid == 0) {
        float bl = 0.f;
        for (int e = 0; e < EE; e++) {
            float f = stats[EE + e] / (float)(NT * KK);
            float P = stats[e] / (float)NT;
            bl += f * P;
        }
        *out_loss = (float)EE * bl + 0.01f * sqrtf(red[0]);
    }
}

extern "C" void kernel_launch(void* const* d_in, const int* in_sizes, int n_in,
                              void* d_out, int out_size, void* d_ws, size_t ws_size,
                              hipStream_t stream) {
    const float* x      = (const float*)d_in[0];
    const float* et     = (const float*)d_in[1];
    const float* ln1_g  = (const float*)d_in[2];
    const float* ln1_b  = (const float*)d_in[3];
    const float* qkv_w  = (const float*)d_in[4];
    const float* qkv_b  = (const float*)d_in[5];
    const float* proj_w = (const float*)d_in[6];
    const float* proj_b = (const float*)d_in[7];
    const float* ln2_g  = (const float*)d_in[8];
    const float* ln2_b  = (const float*)d_in[9];
    const float* fc1_w  = (const float*)d_in[10];
    const float* fc1_b  = (const float*)d_in[11];
    const float* fc2_w  = (const float*)d_in[12];
    const float* fc2_b  = (const float*)d_in[13];
    float* outp = (float*)d_out;
    char* base = (char*)d_ws;

    float* W     = (float*)(base);                       // 131072
    float* stats = (float*)(base + 131072);              // 512
    float* comb  = (float*)(base + 131584);              // 12582912
    float* xmid  = (float*)(base + 12714496);            // 12582912
    u16*   h_hi  = (u16*)  (base + 25297408);            // 6291456
    u16*   h_lo  = (u16*)  (base + 31588864);            // 6291456
    u16*   obf   = (u16*)  (base + 37880320);            // 6291456
    u16*   qk_hi = (u16*)  (base + 44171776);            // 12582912
    u16*   qk_lo = (u16*)  (base + 56754688);            // 12582912
    u16*   vtb   = (u16*)  (base + 69337600);            // 6291456
    u16*   mlp1  = (u16*)  (base + 75629056);            // 25165824
    u16*   qkvTh = (u16*)  (base + 100794880);           // 3538944
    u16*   qkvTl = (u16*)  (base + 104333824);           // 3538944
    u16*   projT = (u16*)  (base + 107872768);           // 1179648
    u16*   fc1T  = (u16*)  (base + 109052416);           // 4718592
    u16*   fc2T  = (u16*)  (base + 113771008);           // 4718592

    hipMemsetAsync(stats, 0, 16 * sizeof(float), stream);
    hipMemsetAsync(comb, 0, (size_t)NOUT * sizeof(float), stream);

    router_kernel<<<NT / 64, 256, 0, stream>>>(x, et, W, stats);

    for (int e = 0; e < EE; e++) {
        ln_kernel<1><<<NT, 256, 0, stream>>>(x, ln1_g + e * CC, ln1_b + e * CC, h_hi, h_lo);
        transpose_w<1><<<dim3(3 * CC / 32, CC / 32), 256, 0, stream>>>(
            qkv_w + (size_t)e * CC * 3 * CC, qkvTh, qkvTl, CC, 3 * CC);
        gemm_qkv_split<<<dim3(3 * CC / 128, NT / 128), 256, 0, stream>>>(
            h_hi, h_lo, qkvTh, qkvTl, qkv_b + (size_t)e * 3 * CC, qk_hi, qk_lo, vtb);
        attn_mfma<<<dim3(SS / 64, HH, BB), 256, 0, stream>>>(qk_hi, qk_lo, vtb, obf);

        transpose_w<0><<<dim3(CC / 32, CC / 32), 256, 0, stream>>>(
            proj_w + (size_t)e * CC * CC, projT, nullptr, CC, CC);
        gemm_mfma<1><<<dim3(CC / 128, NT / 128), 256, 0, stream>>>(
            obf, projT, proj_b + (size_t)e * CC, x, nullptr, xmid, NT, CC, CC);

        ln_kernel<0><<<NT, 256, 0, stream>>>(xmid, ln2_g + e * CC, ln2_b + e * CC, h_hi, nullptr);

        transpose_w<0><<<dim3(MLPH / 32, CC / 32), 256, 0, stream>>>(
            fc1_w + (size_t)e * CC * MLPH, fc1T, nullptr, CC, MLPH);
        gemm_mfma<2><<<dim3(MLPH / 128, NT / 128), 256, 0, stream>>>(
            h_hi, fc1T, fc1_b + (size_t)e * MLPH, nullptr, nullptr, mlp1, NT, MLPH, CC);

        transpose_w<0><<<dim3(CC / 32, MLPH / 32), 256, 0, stream>>>(
            fc2_w + (size_t)e * MLPH * CC, fc2T, nullptr, MLPH, CC);
        gemm_mfma<3><<<dim3(CC / 128, NT / 128), 256, 0, stream>>>(
            mlp1, fc2T, fc2_b + (size_t)e * CC, xmid, W + e, comb, NT, CC, MLPH);
    }

    final_add<<<NOUT / 4 / 256, 256, 0, stream>>>(x, comb, outp);
    loss_kernel<<<1, 256, 0, stream>>>(et, stats, outp + NOUT);
}